// Round 1
// baseline (1560.232 us; speedup 1.0000x reference)
//
#include <hip/hip_runtime.h>

#define H 256
#define W 256
#define BATCH 8
#define CIN 16
#define OC 64
#define TW 32
#define TH 8
#define HW_ (TW + 2)
#define HH_ (TH + 2)
#define PSTR 20  // padded floats per pixel in LDS (16 data + 4 pad) for bank spread

// weight [oc][ic][kh][kw] -> w_t [tap][ic][oc]  (tap = kh*3+kw, ic = g*16+c)
__global__ void wtrans_kernel(const float* __restrict__ w, float* __restrict__ wt) {
    int i = blockIdx.x * 256 + threadIdx.x;  // over 9*64*64 = 36864
    if (i >= 9 * 64 * 64) return;
    int oc  = i & 63;
    int ic  = (i >> 6) & 63;
    int tap = i >> 12;
    wt[i] = w[(oc * 64 + ic) * 9 + tap];
}

__global__ __launch_bounds__(256, 2) void ssconv_kernel(
    const float* __restrict__ x, const int* __restrict__ gidx,
    const float* __restrict__ wt, const float* __restrict__ bias,
    float* __restrict__ out_sel, float* __restrict__ out_idx)
{
    __shared__ float xs[HH_ * HW_ * PSTR];
    __shared__ int   gs[HH_ * HW_];

    const int tid = threadIdx.x;
    const int x0 = blockIdx.x * TW;
    const int y0 = blockIdx.y * TH;
    const int b  = blockIdx.z;

    // ---- stage halo (10 x 34 pixels) ----
    const int NPIX = HH_ * HW_;  // 340
    for (int i = tid; i < NPIX; i += 256) {
        int r  = i / HW_, cc = i % HW_;
        int hi = y0 + r - 1, wi = x0 + cc - 1;
        bool ok = (hi >= 0) && (hi < H) && (wi >= 0) && (wi < W);
        int g = 0;
        float4 v0 = make_float4(0, 0, 0, 0), v1 = v0, v2 = v0, v3 = v0;
        if (ok) {
            g = gidx[((size_t)b * H + hi) * W + wi];
            const float4* src = (const float4*)(x + (((size_t)b * H + hi) * W + wi) * CIN);
            v0 = src[0]; v1 = src[1]; v2 = src[2]; v3 = src[3];
        }
        gs[i] = g;
        float4* dst = (float4*)(xs + i * PSTR);
        dst[0] = v0; dst[1] = v1; dst[2] = v2; dst[3] = v3;
    }
    __syncthreads();

    const int tx = tid & 31, ty = tid >> 5;

    float acc[64];
#pragma unroll
    for (int o4 = 0; o4 < 16; ++o4) {
        float4 bv = ((const float4*)bias)[o4];
        acc[o4 * 4 + 0] = bv.x; acc[o4 * 4 + 1] = bv.y;
        acc[o4 * 4 + 2] = bv.z; acc[o4 * 4 + 3] = bv.w;
    }

    for (int dy = 0; dy < 3; ++dy) {
        for (int dx = 0; dx < 3; ++dx) {
            const int hp = (ty + dy) * HW_ + (tx + dx);
            const int g = gs[hp];
            const float4* xp = (const float4*)(xs + hp * PSTR);
            float xf[16];
            *(float4*)&xf[0]  = xp[0];
            *(float4*)&xf[4]  = xp[1];
            *(float4*)&xf[8]  = xp[2];
            *(float4*)&xf[12] = xp[3];
            const int tap = dy * 3 + dx;
            const float4* wrow = (const float4*)(wt + ((size_t)(tap * 4 + g) * 16) * 64);
#pragma unroll
            for (int c = 0; c < 16; ++c) {
                const float s = xf[c];
#pragma unroll
                for (int o4 = 0; o4 < 16; ++o4) {
                    float4 wv = wrow[c * 16 + o4];
                    acc[o4 * 4 + 0] += s * wv.x;
                    acc[o4 * 4 + 1] += s * wv.y;
                    acc[o4 * 4 + 2] += s * wv.z;
                    acc[o4 * 4 + 3] += s * wv.w;
                }
            }
        }
    }

    // ---- maxout over 4 groups of 16, first-max argmax ----
    float best = acc[0];
    {
#pragma unroll
        for (int c = 1; c < 16; ++c) best = fmaxf(best, acc[c]);
    }
    int bg = 0;
#pragma unroll
    for (int g = 1; g < 4; ++g) {
        float m = acc[g * 16];
#pragma unroll
        for (int c = 1; c < 16; ++c) m = fmaxf(m, acc[g * 16 + c]);
        if (m > best) { best = m; bg = g; }
    }

    float selv[16];
#pragma unroll
    for (int c = 0; c < 16; ++c) {
        float v = acc[c];
        if (bg == 1) v = acc[16 + c];
        if (bg == 2) v = acc[32 + c];
        if (bg == 3) v = acc[48 + c];
        selv[c] = v;
    }

    const int px = x0 + tx, py = y0 + ty;
    const size_t opix = ((size_t)b * H + py) * W + px;
    float4* os = (float4*)(out_sel + opix * 16);
    os[0] = *(float4*)&selv[0];
    os[1] = *(float4*)&selv[4];
    os[2] = *(float4*)&selv[8];
    os[3] = *(float4*)&selv[12];
    out_idx[opix] = (float)bg;
}

extern "C" void kernel_launch(void* const* d_in, const int* in_sizes, int n_in,
                              void* d_out, int out_size, void* d_ws, size_t ws_size,
                              hipStream_t stream) {
    const float* x    = (const float*)d_in[0];
    const int*   gidx = (const int*)d_in[1];
    const float* w    = (const float*)d_in[2];
    const float* bias = (const float*)d_in[3];

    float* wt = (float*)d_ws;  // 9*64*64 floats = 147456 B

    float* out_sel = (float*)d_out;                                  // 8*256*256*16
    float* out_idx = (float*)d_out + (size_t)BATCH * H * W * CIN;    // 8*256*256

    wtrans_kernel<<<(9 * 64 * 64 + 255) / 256, 256, 0, stream>>>(w, wt);

    dim3 grid(W / TW, H / TH, BATCH);
    ssconv_kernel<<<grid, 256, 0, stream>>>(x, gidx, wt, bias, out_sel, out_idx);
}

// Round 2
// 1467.700 us; speedup vs baseline: 1.0630x; 1.0630x over previous
//
#include <hip/hip_runtime.h>

#define H 256
#define W 256
#define BATCH 8
#define CIN 16
#define OC 64
#define TW 32
#define TH 8
#define HW_ (TW + 2)
#define HH_ (TH + 2)
#define PSTR 20  // padded floats per pixel in LDS (16 data + 4 pad)

// weight [oc][ic][kh][kw] -> w_t [tap][ic][oc]  (tap = kh*3+kw, ic = g*16+c)
__global__ void wtrans_kernel(const float* __restrict__ w, float* __restrict__ wt) {
    int i = blockIdx.x * 256 + threadIdx.x;  // over 9*64*64 = 36864
    if (i >= 9 * 64 * 64) return;
    int oc  = i & 63;
    int ic  = (i >> 6) & 63;
    int tap = i >> 12;
    wt[i] = w[(oc * 64 + ic) * 9 + tap];
}

// 16 float4 FMAs into acc[0..15] from a 64-float weight row
#define FMA16(s, wbase)                                         \
    {                                                           \
        const float4* wp_ = (wbase);                            \
        _Pragma("unroll")                                       \
        for (int o4_ = 0; o4_ < 16; ++o4_) {                    \
            float4 wv_ = wp_[o4_];                              \
            acc[o4_].x += (s) * wv_.x;                          \
            acc[o4_].y += (s) * wv_.y;                          \
            acc[o4_].z += (s) * wv_.z;                          \
            acc[o4_].w += (s) * wv_.w;                          \
        }                                                       \
    }

__global__ __launch_bounds__(256, 2) void ssconv_kernel(
    const float* __restrict__ x, const int* __restrict__ gidx,
    const float* __restrict__ wt, const float* __restrict__ bias,
    float* __restrict__ out_sel, float* __restrict__ out_idx)
{
    __shared__ float xs[HH_ * HW_ * PSTR];
    __shared__ int   gs[HH_ * HW_];

    const int tid = threadIdx.x;
    const int x0 = blockIdx.x * TW;
    const int y0 = blockIdx.y * TH;
    const int b  = blockIdx.z;

    // ---- stage halo (10 x 34 pixels) ----
    const int NPIX = HH_ * HW_;  // 340
    for (int i = tid; i < NPIX; i += 256) {
        int r  = i / HW_, cc = i % HW_;
        int hi = y0 + r - 1, wi = x0 + cc - 1;
        bool ok = (hi >= 0) && (hi < H) && (wi >= 0) && (wi < W);
        int g = 0;
        float4 v0 = make_float4(0, 0, 0, 0), v1 = v0, v2 = v0, v3 = v0;
        if (ok) {
            g = gidx[((size_t)b * H + hi) * W + wi];
            const float4* src = (const float4*)(x + (((size_t)b * H + hi) * W + wi) * CIN);
            v0 = src[0]; v1 = src[1]; v2 = src[2]; v3 = src[3];
        }
        gs[i] = g;
        float4* dst = (float4*)(xs + i * PSTR);
        dst[0] = v0; dst[1] = v1; dst[2] = v2; dst[3] = v3;
    }
    __syncthreads();

    const int tx = tid & 31, ty = tid >> 5;

    float4 acc[16];
#pragma unroll
    for (int o4 = 0; o4 < 16; ++o4) acc[o4] = ((const float4*)bias)[o4];

#pragma unroll 1
    for (int dy = 0; dy < 3; ++dy) {
#pragma unroll 1
        for (int dx = 0; dx < 3; ++dx) {
            const int hp = (ty + dy) * HW_ + (tx + dx);
            const int g = gs[hp];
            const float4* xp = (const float4*)(xs + hp * PSTR);
            const float4* wrow =
                (const float4*)wt + (size_t)(((dy * 3 + dx) * 4 + g)) * 256;
            float4 xv0 = xp[0], xv1 = xp[1], xv2 = xp[2], xv3 = xp[3];
            FMA16(xv0.x, wrow + 0 * 16);
            FMA16(xv0.y, wrow + 1 * 16);
            FMA16(xv0.z, wrow + 2 * 16);
            FMA16(xv0.w, wrow + 3 * 16);
            FMA16(xv1.x, wrow + 4 * 16);
            FMA16(xv1.y, wrow + 5 * 16);
            FMA16(xv1.z, wrow + 6 * 16);
            FMA16(xv1.w, wrow + 7 * 16);
            FMA16(xv2.x, wrow + 8 * 16);
            FMA16(xv2.y, wrow + 9 * 16);
            FMA16(xv2.z, wrow + 10 * 16);
            FMA16(xv2.w, wrow + 11 * 16);
            FMA16(xv3.x, wrow + 12 * 16);
            FMA16(xv3.y, wrow + 13 * 16);
            FMA16(xv3.z, wrow + 14 * 16);
            FMA16(xv3.w, wrow + 15 * 16);
        }
    }

    // ---- per-group max (groups of 4 float4 = 16 channels) ----
    float m0, m1, m2, m3;
    {
        float4 a = acc[0], b4 = acc[1], c4 = acc[2], d4 = acc[3];
        m0 = fmaxf(fmaxf(fmaxf(a.x, a.y), fmaxf(a.z, a.w)),
                   fmaxf(fmaxf(fmaxf(b4.x, b4.y), fmaxf(b4.z, b4.w)),
                         fmaxf(fmaxf(fmaxf(c4.x, c4.y), fmaxf(c4.z, c4.w)),
                               fmaxf(fmaxf(d4.x, d4.y), fmaxf(d4.z, d4.w)))));
    }
    {
        float4 a = acc[4], b4 = acc[5], c4 = acc[6], d4 = acc[7];
        m1 = fmaxf(fmaxf(fmaxf(a.x, a.y), fmaxf(a.z, a.w)),
                   fmaxf(fmaxf(fmaxf(b4.x, b4.y), fmaxf(b4.z, b4.w)),
                         fmaxf(fmaxf(fmaxf(c4.x, c4.y), fmaxf(c4.z, c4.w)),
                               fmaxf(fmaxf(d4.x, d4.y), fmaxf(d4.z, d4.w)))));
    }
    {
        float4 a = acc[8], b4 = acc[9], c4 = acc[10], d4 = acc[11];
        m2 = fmaxf(fmaxf(fmaxf(a.x, a.y), fmaxf(a.z, a.w)),
                   fmaxf(fmaxf(fmaxf(b4.x, b4.y), fmaxf(b4.z, b4.w)),
                         fmaxf(fmaxf(fmaxf(c4.x, c4.y), fmaxf(c4.z, c4.w)),
                               fmaxf(fmaxf(d4.x, d4.y), fmaxf(d4.z, d4.w)))));
    }
    {
        float4 a = acc[12], b4 = acc[13], c4 = acc[14], d4 = acc[15];
        m3 = fmaxf(fmaxf(fmaxf(a.x, a.y), fmaxf(a.z, a.w)),
                   fmaxf(fmaxf(fmaxf(b4.x, b4.y), fmaxf(b4.z, b4.w)),
                         fmaxf(fmaxf(fmaxf(c4.x, c4.y), fmaxf(c4.z, c4.w)),
                               fmaxf(fmaxf(d4.x, d4.y), fmaxf(d4.z, d4.w)))));
    }

    // first-max argmax (strict > keeps lowest index on ties, matches jnp.argmax)
    int bg = 0;
    float best = m0;
    if (m1 > best) { best = m1; bg = 1; }
    if (m2 > best) { best = m2; bg = 2; }
    if (m3 > best) { best = m3; bg = 3; }

    const int px = x0 + tx, py = y0 + ty;
    const size_t opix = ((size_t)b * H + py) * W + px;
    float4* os = (float4*)(out_sel + opix * 16);

#pragma unroll
    for (int c4 = 0; c4 < 4; ++c4) {
        float4 s0 = acc[c4], s1 = acc[4 + c4], s2 = acc[8 + c4], s3 = acc[12 + c4];
        float4 r;
        r.x = (bg == 0) ? s0.x : (bg == 1) ? s1.x : (bg == 2) ? s2.x : s3.x;
        r.y = (bg == 0) ? s0.y : (bg == 1) ? s1.y : (bg == 2) ? s2.y : s3.y;
        r.z = (bg == 0) ? s0.z : (bg == 1) ? s1.z : (bg == 2) ? s2.z : s3.z;
        r.w = (bg == 0) ? s0.w : (bg == 1) ? s1.w : (bg == 2) ? s2.w : s3.w;
        os[c4] = r;
    }
    out_idx[opix] = (float)bg;
}

extern "C" void kernel_launch(void* const* d_in, const int* in_sizes, int n_in,
                              void* d_out, int out_size, void* d_ws, size_t ws_size,
                              hipStream_t stream) {
    const float* x    = (const float*)d_in[0];
    const int*   gidx = (const int*)d_in[1];
    const float* w    = (const float*)d_in[2];
    const float* bias = (const float*)d_in[3];

    float* wt = (float*)d_ws;  // 9*64*64 floats = 147456 B

    float* out_sel = (float*)d_out;                                  // 8*256*256*16
    float* out_idx = (float*)d_out + (size_t)BATCH * H * W * CIN;    // 8*256*256

    wtrans_kernel<<<(9 * 64 * 64 + 255) / 256, 256, 0, stream>>>(w, wt);

    dim3 grid(W / TW, H / TH, BATCH);
    ssconv_kernel<<<grid, 256, 0, stream>>>(x, gidx, wt, bias, out_sel, out_idx);
}

// Round 4
// 210.842 us; speedup vs baseline: 7.4000x; 6.9611x over previous
//
#include <hip/hip_runtime.h>

#define H 256
#define W 256
#define BATCH 8
#define CIN 16
#define TW 32
#define TH 4
#define HWC (TW + 2)        // 34 halo cols
#define HHC (TH + 2)        // 6 halo rows
#define NHALO (HWC * HHC)   // 204 halo pixels
#define FIX_CAP 16384
#define GAP_TAU 1e-3f

typedef __attribute__((ext_vector_type(8))) short short8;       // 8 fp16 bit-patterns
typedef __attribute__((ext_vector_type(8))) _Float16 half8;     // MFMA A/B frag
typedef __attribute__((ext_vector_type(4))) float f32x4;        // MFMA C/D frag

union S8H8 { short8 s; half8 h; };
__device__ __forceinline__ half8 as_h8(short8 s) { S8H8 u; u.s = s; return u.h; }
union HU { _Float16 h; unsigned short u; };
__device__ __forceinline__ unsigned short f2h_bits(float f) { HU u; u.h = (_Float16)f; return u.u; }
__device__ __forceinline__ float h2f(unsigned short b) { HU u; u.u = b; return (float)u.h; }

__device__ __forceinline__ float4 add4(float4 a, float4 b) {
    return make_float4(a.x + b.x, a.y + b.y, a.z + b.z, a.w + b.w);
}
__device__ __forceinline__ float max4(float4 a) {
    return fmaxf(fmaxf(a.x, a.y), fmaxf(a.z, a.w));
}

// weight [oc][ic][3][3] fp32 -> wt [tap][sel(0=hi,1=lo*2048)][n=oc][k=ic] fp16 bits; w pre-scaled x64
__global__ void wprep_kernel(const float* __restrict__ w, unsigned short* __restrict__ wt) {
    int i = blockIdx.x * 256 + threadIdx.x;   // 9*2*64*64 = 73728
    if (i >= 73728) return;
    int k   = i & 63;
    int n   = (i >> 6) & 63;
    int sel = (i >> 12) & 1;
    int tap = i >> 13;
    float v = w[(n * 64 + k) * 9 + tap] * 64.0f;
    unsigned short hb = f2h_bits(v);
    unsigned short ob = sel ? f2h_bits((v - h2f(hb)) * 2048.0f) : hb;
    wt[(((tap * 2 + sel) * 64) + n) * 64 + k] = ob;
}

#define CVT(F, VH, VL, J) { unsigned short hb_ = f2h_bits(F); \
    VH[J] = (short)hb_; VL[J] = (short)f2h_bits(((F) - h2f(hb_)) * 2048.0f); }

__global__ __launch_bounds__(256, 2) void ssconv_mfma_kernel(
    const float* __restrict__ x, const int* __restrict__ gidx,
    const unsigned short* __restrict__ wt, const float* __restrict__ bias,
    float* __restrict__ out_sel, float* __restrict__ out_idx,
    unsigned* __restrict__ fix_cnt, unsigned* __restrict__ fix_list)
{
    __shared__ unsigned short hHi[NHALO * 16];            // 6528 B (xh)
    __shared__ unsigned short hLo[NHALO * 16];            // 6528 B (xl*2048)
    __shared__ int gsL[NHALO];                            // 816 B
    // union: B-tap staging (rows of 72 shorts) during K-loop, out scratch in epilogue
    __shared__ __align__(16) unsigned short bufS[17408];  // 34816 B

    const int tid = threadIdx.x;
    const int x0 = blockIdx.x * TW;
    const int y0 = blockIdx.y * TH;
    const int bz = blockIdx.z;

    // ---- stage halo as fp16 hi/lo + group map ----
    if (tid < NHALO) {
        int r = tid / HWC, c = tid % HWC;
        int hy = y0 + r - 1, hx = x0 + c - 1;
        bool ok = (hy >= 0) && (hy < H) && (hx >= 0) && (hx < W);
        float4 a0 = make_float4(0, 0, 0, 0), a1 = a0, a2 = a0, a3 = a0;
        int g = 0;
        if (ok) {
            const float4* src = (const float4*)(x + (((size_t)bz * H + hy) * W + hx) * CIN);
            a0 = src[0]; a1 = src[1]; a2 = src[2]; a3 = src[3];
            g = gidx[((size_t)bz * H + hy) * W + hx];
        }
        gsL[tid] = g;
        short8 vh0, vl0, vh1, vl1;
        CVT(a0.x, vh0, vl0, 0) CVT(a0.y, vh0, vl0, 1) CVT(a0.z, vh0, vl0, 2) CVT(a0.w, vh0, vl0, 3)
        CVT(a1.x, vh0, vl0, 4) CVT(a1.y, vh0, vl0, 5) CVT(a1.z, vh0, vl0, 6) CVT(a1.w, vh0, vl0, 7)
        CVT(a2.x, vh1, vl1, 0) CVT(a2.y, vh1, vl1, 1) CVT(a2.z, vh1, vl1, 2) CVT(a2.w, vh1, vl1, 3)
        CVT(a3.x, vh1, vl1, 4) CVT(a3.y, vh1, vl1, 5) CVT(a3.z, vh1, vl1, 6) CVT(a3.w, vh1, vl1, 7)
        *(short8*)&hHi[tid * 16 + 0] = vh0;
        *(short8*)&hHi[tid * 16 + 8] = vh1;
        *(short8*)&hLo[tid * 16 + 0] = vl0;
        *(short8*)&hLo[tid * 16 + 8] = vl1;
    }

    const int wvid = tid >> 6;        // wave id 0..3 -> tile row
    const int L    = tid & 63;
    const int q    = L >> 4;          // quad
    const int lm   = L & 15;

    // ---- stage B(tap=0) ----
    {
        const unsigned short* wsrc = wt;
        for (int it = 0; it < 4; ++it) {
            int i = it * 256 + tid;       // sel(1)|n(6)|ko(3)
            int ko = i & 7, n = (i >> 3) & 63, sel = i >> 9;
            short8 v = *(const short8*)(wsrc + (sel * 64 + n) * 64 + ko * 8);
            *(short8*)(bufS + (sel * 64 + n) * 72 + ko * 8) = v;
        }
    }
    __syncthreads();

    f32x4 acc0h[4] = {}, acc1h[4] = {};   // xh*wh terms (units: 64x true)
    f32x4 acc0l[4] = {}, acc1l[4] = {};   // cross terms (units: 64*2048x true)

#pragma unroll 1
    for (int tap = 0; tap < 9; ++tap) {
        const int dy = tap / 3, dx = tap % 3;
        const int hb0 = (wvid + dy) * HWC + lm + dx;   // m-tile 0 halo pixel
        const int hb1 = hb0 + 16;                      // m-tile 1
        const int g0 = gsL[hb0];
        const int g1 = gsL[hb1];

#pragma unroll
        for (int ks = 0; ks < 2; ++ks) {
            const int gk = ks * 2 + (q >> 1);
            const int c0 = (q & 1) * 8;
            short8 z = (short8)0;
            short8 ah0 = *(const short8*)&hHi[hb0 * 16 + c0];
            short8 al0 = *(const short8*)&hLo[hb0 * 16 + c0];
            short8 ah1 = *(const short8*)&hHi[hb1 * 16 + c0];
            short8 al1 = *(const short8*)&hLo[hb1 * 16 + c0];
            bool m0 = (g0 == gk), m1 = (g1 == gk);
            ah0 = m0 ? ah0 : z;  al0 = m0 ? al0 : z;
            ah1 = m1 ? ah1 : z;  al1 = m1 ? al1 : z;

            short8 bh[4];
#pragma unroll
            for (int nt = 0; nt < 4; ++nt)
                bh[nt] = *(const short8*)(bufS + (nt * 16 + lm) * 72 + ks * 32 + q * 8);
#pragma unroll
            for (int nt = 0; nt < 4; ++nt) {
                acc0h[nt] = __builtin_amdgcn_mfma_f32_16x16x32_f16(as_h8(ah0), as_h8(bh[nt]), acc0h[nt], 0, 0, 0);
                acc1h[nt] = __builtin_amdgcn_mfma_f32_16x16x32_f16(as_h8(ah1), as_h8(bh[nt]), acc1h[nt], 0, 0, 0);
                acc0l[nt] = __builtin_amdgcn_mfma_f32_16x16x32_f16(as_h8(al0), as_h8(bh[nt]), acc0l[nt], 0, 0, 0);
                acc1l[nt] = __builtin_amdgcn_mfma_f32_16x16x32_f16(as_h8(al1), as_h8(bh[nt]), acc1l[nt], 0, 0, 0);
            }
#pragma unroll
            for (int nt = 0; nt < 4; ++nt) {
                short8 bl = *(const short8*)(bufS + (64 + nt * 16 + lm) * 72 + ks * 32 + q * 8);
                acc0l[nt] = __builtin_amdgcn_mfma_f32_16x16x32_f16(as_h8(ah0), as_h8(bl), acc0l[nt], 0, 0, 0);
                acc1l[nt] = __builtin_amdgcn_mfma_f32_16x16x32_f16(as_h8(ah1), as_h8(bl), acc1l[nt], 0, 0, 0);
            }
        }
        __syncthreads();
        if (tap < 8) {
            const unsigned short* wsrc = wt + (size_t)(tap + 1) * 8192;
            for (int it = 0; it < 4; ++it) {
                int i = it * 256 + tid;
                int ko = i & 7, n = (i >> 3) & 63, sel = i >> 9;
                short8 v = *(const short8*)(wsrc + (sel * 64 + n) * 64 + ko * 8);
                *(short8*)(bufS + (sel * 64 + n) * 72 + ko * 8) = v;
            }
            __syncthreads();
        }
    }

    // ---- epilogue: combine + dump to LDS (row m = q*4+r, col n = lm) ----
    const float SH = 0.015625f;               // 1/64
    const float SL = 7.62939453125e-6f;       // 1/(64*2048)
    float* outS = (float*)bufS;               // per-wave region: 32 px * 68 floats
#pragma unroll
    for (int nt = 0; nt < 4; ++nt) {
#pragma unroll
        for (int r = 0; r < 4; ++r) {
            int xcol0 = q * 4 + r;
            outS[wvid * 2176 + xcol0 * 68 + nt * 16 + lm] =
                acc0h[nt][r] * SH + acc0l[nt][r] * SL;
            outS[wvid * 2176 + (16 + xcol0) * 68 + nt * 16 + lm] =
                acc1h[nt][r] * SH + acc1l[nt][r] * SL;
        }
    }
    __syncthreads();

    // ---- per-pixel maxout/argmax/select: 2 threads per pixel (32 ch each) ----
    {
        int p  = tid >> 1;           // tile pixel 0..127
        int hh = tid & 1;            // channel half
        int pw = p >> 5, px_ = p & 31;
        const float4* srcp = (const float4*)(outS + pw * 2176 + px_ * 68 + hh * 32);
        const float4* bb = (const float4*)(bias + hh * 32);
        float4 r0 = add4(srcp[0], bb[0]), r1 = add4(srcp[1], bb[1]);
        float4 r2 = add4(srcp[2], bb[2]), r3 = add4(srcp[3], bb[3]);
        float4 r4 = add4(srcp[4], bb[4]), r5 = add4(srcp[5], bb[5]);
        float4 r6 = add4(srcp[6], bb[6]), r7 = add4(srcp[7], bb[7]);

        float ma = fmaxf(fmaxf(max4(r0), max4(r1)), fmaxf(max4(r2), max4(r3)));
        float mb = fmaxf(fmaxf(max4(r4), max4(r5)), fmaxf(max4(r6), max4(r7)));
        float pa = __shfl_xor(ma, 1, 64);
        float pb = __shfl_xor(mb, 1, 64);
        float s0, s1, s2, s3;
        if (hh == 0) { s0 = ma; s1 = mb; s2 = pa; s3 = pb; }
        else         { s0 = pa; s1 = pb; s2 = ma; s3 = mb; }
        int bg = 0; float best = s0;
        if (s1 > best) { best = s1; bg = 1; }
        if (s2 > best) { best = s2; bg = 2; }
        if (s3 > best) { best = s3; bg = 3; }

        int gy = y0 + pw, gx = x0 + px_;
        size_t opix = ((size_t)bz * H + gy) * W + gx;
        if ((bg >> 1) == hh) {
            bool useB = (bg & 1) != 0;
            float4 o0 = useB ? r4 : r0, o1 = useB ? r5 : r1;
            float4 o2 = useB ? r6 : r2, o3 = useB ? r7 : r3;
            float4* os = (float4*)(out_sel + opix * 16);
            os[0] = o0; os[1] = o1; os[2] = o2; os[3] = o3;
        }
        if (hh == 0) {
            out_idx[opix] = (float)bg;
            // flag near-ties for fp64 fix-up
            float o1v = (bg == 0) ? s1 : s0;
            float o2v = (bg <= 1) ? s2 : s1;
            float o3v = (bg <= 2) ? s3 : s2;
            float second = fmaxf(o1v, fmaxf(o2v, o3v));
            if (best - second < GAP_TAU) {
                unsigned slot = atomicAdd(fix_cnt, 1u);
                if (slot < FIX_CAP) fix_list[slot] = (unsigned)opix;
            }
        }
    }
}

// fp64 exact recompute of flagged pixels; one wave per pixel, lane = oc
__global__ void fixup_kernel(const float* __restrict__ x, const int* __restrict__ gidx,
                             const float* __restrict__ w, const float* __restrict__ bias,
                             float* __restrict__ out_sel, float* __restrict__ out_idx,
                             const unsigned* __restrict__ fix_cnt,
                             const unsigned* __restrict__ fix_list)
{
    unsigned n = *fix_cnt;
    if (n > FIX_CAP) n = FIX_CAP;
    const int lane = threadIdx.x & 63;
    const int nwaves = gridDim.x * (blockDim.x >> 6);
    unsigned widx = blockIdx.x * (blockDim.x >> 6) + (threadIdx.x >> 6);

    for (; widx < n; widx += nwaves) {
        unsigned opix = fix_list[widx];
        int b  = opix >> 16;
        int y  = (opix >> 8) & 255;
        int xc = opix & 255;
        double acc = (double)bias[lane];
        for (int dy = 0; dy < 3; ++dy) {
            int yy = y + dy - 1;
            if (yy < 0 || yy >= H) continue;
            for (int dx = 0; dx < 3; ++dx) {
                int xx = xc + dx - 1;
                if (xx < 0 || xx >= W) continue;
                size_t pix = ((size_t)b * H + yy) * W + xx;
                int g = gidx[pix];
                const float* xp = x + pix * 16;
                const float* wp = w + (size_t)(lane * 64 + g * 16) * 9 + (dy * 3 + dx);
#pragma unroll
                for (int c = 0; c < 16; ++c)
                    acc = fma((double)wp[c * 9], (double)xp[c], acc);
            }
        }
        // group max within 16-lane clusters
        double m = acc;
        m = fmax(m, __shfl_xor(m, 1, 64));
        m = fmax(m, __shfl_xor(m, 2, 64));
        m = fmax(m, __shfl_xor(m, 4, 64));
        m = fmax(m, __shfl_xor(m, 8, 64));
        double g0 = __shfl(m, 0, 64), g1 = __shfl(m, 16, 64);
        double g2 = __shfl(m, 32, 64), g3 = __shfl(m, 48, 64);
        int bg = 0; double bb = g0;
        if (g1 > bb) { bb = g1; bg = 1; }
        if (g2 > bb) { bb = g2; bg = 2; }
        if (g3 > bb) { bb = g3; bg = 3; }
        if ((lane >> 4) == bg) out_sel[(size_t)opix * 16 + (lane & 15)] = (float)acc;
        if (lane == 0) out_idx[opix] = (float)bg;
    }
}

extern "C" void kernel_launch(void* const* d_in, const int* in_sizes, int n_in,
                              void* d_out, int out_size, void* d_ws, size_t ws_size,
                              hipStream_t stream) {
    const float* x    = (const float*)d_in[0];
    const int*   gidx = (const int*)d_in[1];
    const float* w    = (const float*)d_in[2];
    const float* bias = (const float*)d_in[3];

    unsigned short* wt = (unsigned short*)d_ws;                    // 147456 B
    unsigned* fix_cnt  = (unsigned*)((char*)d_ws + 147456);        // 16 B
    unsigned* fix_list = (unsigned*)((char*)d_ws + 147472);        // 64 KB

    float* out_sel = (float*)d_out;                               // 8*256*256*16
    float* out_idx = (float*)d_out + (size_t)BATCH * H * W * CIN; // 8*256*256

    hipMemsetAsync(fix_cnt, 0, 16, stream);
    wprep_kernel<<<288, 256, 0, stream>>>(w, wt);

    dim3 grid(W / TW, H / TH, BATCH);   // 8 x 64 x 8 = 4096 blocks
    ssconv_mfma_kernel<<<grid, 256, 0, stream>>>(x, gidx, wt, bias, out_sel, out_idx,
                                                 fix_cnt, fix_list);
    fixup_kernel<<<256, 256, 0, stream>>>(x, gidx, w, bias, out_sel, out_idx,
                                          fix_cnt, fix_list);
}